// Round 10
// baseline (5729.866 us; speedup 1.0000x reference)
//
#include <hip/hip_runtime.h>
#include <math.h>

#define NWG 128
#define TPB 1024

static constexpr int Bc=128, Ic=256, Hc=512, NCc=16, Tc=24, Mc=14;
static constexpr int Y_SZ  = Bc*NCc*Tc;     // 49152
static constexpr int P_OFF = Y_SZ;          // 49152
static constexpr int N_OFF = Y_SZ + Bc;     // 49280

// ws layout (floats) -- total 360448 floats = 1.375 MiB (proven budget)
static constexpr int XSZ    = Ic*Bc;                 // 32768
static constexpr int HSZ    = Hc*Bc;                 // 65536
static constexpr int PSZ    = Bc*Bc;                 // 16384
static constexpr int XS_OFF = 0;                     // xs[2][256][128]
static constexpr int HB_OFF = XS_OFF + 2*XSZ;        // hbuf[2][512][128]
static constexpr int SC_OFF = HB_OFF + 2*HSZ;        // stc[2][512][128]
static constexpr int HP_OFF = SC_OFF + 2*HSZ;        // hpp[2][128][128]

// Hierarchical barrier: 16 groups x 8 blocks; monotonic watermarks, 64B lines.
__device__ __align__(64) unsigned g_bcnt[16][16];
__device__ __align__(64) unsigned g_bgen[16][16];
__device__ __align__(64) unsigned g_brc[16];
__device__ __align__(64) unsigned g_brg[16];

__device__ __forceinline__ float sigm(float v){ return 1.0f/(1.0f+expf(-v)); }

// PRODUCER: system-scope write-through stores (sc0 sc1) -> coherent at IF.
__device__ __forceinline__ void gstore(float* p, float v){
  __hip_atomic_store(p, v, __ATOMIC_RELAXED, __HIP_MEMORY_SCOPE_SYSTEM);
}
// CONSUMER: plain cached loads; coherence comes from the per-tick
// agent-acquire fence at gsync exit (r6-proven scheme).
__device__ __forceinline__ float gload(const float* p){ return *p; }

// Two-level generation barrier (r6-proven) + consumer-side acquire fence.
__device__ __forceinline__ void gsync(int w){
  __syncthreads();
  if (threadIdx.x == 0) {
    asm volatile("" ::: "memory");
    const int g = w >> 3;                    // 16 groups of 8
    unsigned prev = __hip_atomic_fetch_add(&g_bcnt[g][0], 1u, __ATOMIC_RELAXED, __HIP_MEMORY_SCOPE_SYSTEM);
    unsigned ep   = prev >> 3;               // barrier episode
    if ((prev & 7u) == 7u) {
      unsigned rprev = __hip_atomic_fetch_add(&g_brc[0], 1u, __ATOMIC_RELAXED, __HIP_MEMORY_SCOPE_SYSTEM);
      if ((rprev & 15u) == 15u) {
        __hip_atomic_store(&g_brg[0], (rprev >> 4) + 1u, __ATOMIC_RELEASE, __HIP_MEMORY_SCOPE_SYSTEM);
      } else {
        while ((int)(__hip_atomic_load(&g_brg[0], __ATOMIC_RELAXED, __HIP_MEMORY_SCOPE_SYSTEM) - (ep + 1u)) < 0)
          __builtin_amdgcn_s_sleep(1);
      }
      __hip_atomic_store(&g_bgen[g][0], ep + 1u, __ATOMIC_RELEASE, __HIP_MEMORY_SCOPE_SYSTEM);
    } else {
      while ((int)(__hip_atomic_load(&g_bgen[g][0], __ATOMIC_RELAXED, __HIP_MEMORY_SCOPE_SYSTEM) - (ep + 1u)) < 0)
        __builtin_amdgcn_s_sleep(1);
    }
    asm volatile("" ::: "memory");
  }
  __syncthreads();
  __builtin_amdgcn_fence(__ATOMIC_ACQUIRE, "agent");   // inv L1 + XCD L2
}

// Partial GEMV, CODE-SIZE-MINIMIZED: runtime loop over group-quads (4 groups
// of 8 k per iteration), depth-4 prefetch ring with STATIC mod-4 buffer
// indices. #pragma unroll 1 keeps one ~700-instr body in I$ instead of a
// 5-10x unrolled stream (the r6 kernel's tick body overflowed the 32KB I$).
#define GEMV_LOOP(NGR, SRC, WR, DWP, DACC)                                    \
  {                                                                           \
    float pv[4][8];                                                           \
    _Pragma("unroll")                                                         \
    for (int d=0; d<4 && d<(NGR); ++d) {                                      \
      _Pragma("unroll")                                                       \
      for (int u=0; u<8; ++u) pv[d][u] = gload((SRC) + (d*8+u)*Bc);           \
    }                                                                         \
    _Pragma("unroll 1")                                                       \
    for (int ii=0; ii<(NGR)/4; ++ii) {                                        \
      const bool more = (ii+1 < (NGR)/4);                                     \
      _Pragma("unroll")                                                       \
      for (int gg=0; gg<4; ++gg) {                                            \
        const int g = ii*4+gg;                                                \
        const float h0=pv[gg][0], h1=pv[gg][1], h2=pv[gg][2], h3=pv[gg][3];   \
        const float h4=pv[gg][4], h5=pv[gg][5], h6=pv[gg][6], h7=pv[gg][7];   \
        if (more) {                                                           \
          _Pragma("unroll")                                                   \
          for (int u=0; u<8; ++u) pv[gg][u] = gload((SRC) + ((g+4)*8+u)*Bc);  \
        }                                                                     \
        const int kb = g*8;                                                   \
        _Pragma("unroll")                                                     \
        for (int r=0; r<16; ++r) {                                            \
          float p = part[r];                                                  \
          p = fmaf(h0,(WR)[r][kb+0],p); p = fmaf(h1,(WR)[r][kb+1],p);         \
          p = fmaf(h2,(WR)[r][kb+2],p); p = fmaf(h3,(WR)[r][kb+3],p);         \
          p = fmaf(h4,(WR)[r][kb+4],p); p = fmaf(h5,(WR)[r][kb+5],p);         \
          p = fmaf(h6,(WR)[r][kb+6],p); p = fmaf(h7,(WR)[r][kb+7],p);         \
          part[r] = p;                                                        \
        }                                                                     \
        DACC = fmaf(h0,(DWP)[kb+0],DACC); DACC = fmaf(h1,(DWP)[kb+1],DACC);   \
        DACC = fmaf(h2,(DWP)[kb+2],DACC); DACC = fmaf(h3,(DWP)[kb+3],DACC);   \
        DACC = fmaf(h4,(DWP)[kb+4],DACC); DACC = fmaf(h5,(DWP)[kb+5],DACC);   \
        DACC = fmaf(h6,(DWP)[kb+6],DACC); DACC = fmaf(h7,(DWP)[kb+7],DACC);   \
      }                                                                       \
    }                                                                         \
  }

__global__ __launch_bounds__(TPB, 4) void act_lstm_kernel(
    const float* __restrict__ x,   const float* __restrict__ Wih,
    const float* __restrict__ Whh, const float* __restrict__ bih,
    const float* __restrict__ bhh, const float* __restrict__ hw,
    const float* __restrict__ hbp, const float* __restrict__ dw,
    const float* __restrict__ db,  float* __restrict__ out,
    float* __restrict__ ws)
{
  const int w    = blockIdx.x;
  const int tid  = threadIdx.x;
  const int lane = tid & 63;
  const int wid  = __builtin_amdgcn_readfirstlane(tid >> 6); // 0..15
  const int bh   = wid & 1;
  const int k8   = wid >> 1;         // 0..7 : k-eighth (h) / i-eighth (x)
  const int b    = bh*64 + lane;
  const int jb   = w * 4;            // block owns j = jb..jb+3
  const int jpair= k8 & 3;           // cell ownership for wid<8
  const int jmine= jb + jpair;       // valid for wid<8
  const int kq   = k8 * 64;          // h/st k-slice base
  const int iq   = k8 * 32;          // x i-slice base
  const bool cellw = (wid < 8);

  float* xs   = ws + XS_OFF;
  float* hbuf = ws + HB_OFF;
  float* stc  = ws + SC_OFF;
  float* hpp  = ws + HP_OFF;

  __shared__ float lds_red[8*8*128];   // [k8][row-chunk 8][b] = 32 KB
  __shared__ float lds_hp[4*128];
  __shared__ float lds_hq[8*128];
  __shared__ float lds_pmh[128];
  __shared__ float lds_dec[8*128];
  __shared__ unsigned lds_u[2];

  const float* whp[16];
  const float* wip[16];
  #pragma unroll
  for (int r=0; r<16; ++r) {
    const int grow = (r>>2)*512 + jb + (r&3);
    whp[r] = Whh + grow*Hc + kq;
    wip[r] = Wih + grow*Ic + iq;
  }
  float bsum[4];
  #pragma unroll
  for (int ty=0; ty<4; ++ty) bsum[ty] = bih[ty*512 + jmine] + bhh[ty*512 + jmine];
  const float hwj = hw[jmine];
  const float hb0 = hbp[0];
  const float* dwq = dw + (w < NCc ? w : 0)*Hc + kq;   // decoder class = w for w<16
  const float dbv  = db[w < NCc ? w : 0];

  // -------- prologue: stage x[:,:,0] --------
  if (tid < 256) {
    int g = w*256 + tid;             // 128*256 = 32768 = XSZ
    int i = g >> 7, bb = g & 127;
    gstore(xs + i*Bc + bb, x[bb*(Ic*Tc) + i*Tc + 0]);
  }
  gsync(w);

  // -------- persistent state --------
  float c = 0.f;                      // cell (jmine, b) for wid<8
  float st_run=0.f, ct_run=0.f, prev_pm=0.f;
  float cumw=0.f, prevw=0.f, ntfw=0.f, rtvw=0.f, psumw=0.f;  // wid<2: b'=wid*64+lane
  bool  ntsetw=false;
  int   gt = 0;
  int   lastpar = 0;

  for (int t=0; t<Tc; ++t) {
    float xg[4];
    for (int mm=0;; ++mm) {
      float part[16];
      float hacc[4];
      float dacc = 0.f;

      // ---------- phase A ----------
      if (mm == 0) {
        // x-GEMV
        #pragma unroll
        for (int r=0; r<16; ++r) part[r]=0.f;
        {
          const float* xsr = xs + (t&1)*XSZ + iq*Bc + b;
          float jnk = 0.f;
          GEMV_LOOP(4, xsr, wip, dwq, jnk)
        }
        // reduce x partials, 2 chunks of 8 rows
        #pragma unroll
        for (int ch=0; ch<2; ++ch) {
          #pragma unroll
          for (int rr=0; rr<8; ++rr) lds_red[(k8*8+rr)*128 + b] = part[ch*8+rr];
          __syncthreads();
          if (cellw) {
            #pragma unroll
            for (int tt=0; tt<2; ++tt) {
              const int ty = ch*2+tt;
              const int rr = (ty*4+jpair) & 7;
              float s=0.f;
              #pragma unroll
              for (int kk8=0; kk8<8; ++kk8) s += lds_red[(kk8*8+rr)*128 + b];
              xg[ty] = bsum[ty] + s;
            }
          }
          __syncthreads();
        }
        // stage next timestep's x slice
        if (t+1 < Tc && tid < 256) {
          int g = w*256 + tid;
          int i = g >> 7, bb = g & 127;
          gstore(xs + ((t+1)&1)*XSZ + i*Bc + bb, x[bb*(Ic*Tc) + i*Tc + (t+1)]);
        }
        #pragma unroll
        for (int r=0; r<16; ++r) part[r]=0.f;
      } else {
        #pragma unroll
        for (int r=0; r<16; ++r) part[r]=0.f;
      }

      // h-GEMV: SINGLE expansion; source selected at runtime.
      {
        const float* hs;
        bool do_h;
        if (mm == 0) { hs = stc + lastpar*HSZ + kq*Bc + b; do_h = (t > 0); }
        else         { hs = hbuf + ((gt-1)&1)*HSZ + kq*Bc + b; do_h = true; }
        if (do_h) {
          GEMV_LOOP(8, hs, whp, dwq, dacc)
        }
      }

      // ---------- reduce h/st partials (2 chunks), + decoder ----------
      if (mm == 0) lds_dec[k8*128 + b] = dacc;
      #pragma unroll
      for (int ch=0; ch<2; ++ch) {
        #pragma unroll
        for (int rr=0; rr<8; ++rr) lds_red[(k8*8+rr)*128 + b] = part[ch*8+rr];
        __syncthreads();
        if (cellw) {
          #pragma unroll
          for (int tt=0; tt<2; ++tt) {
            const int ty = ch*2+tt;
            const int rr = (ty*4+jpair) & 7;
            float s=0.f;
            #pragma unroll
            for (int kk8=0; kk8<8; ++kk8) s += lds_red[(kk8*8+rr)*128 + b];
            hacc[ty] = s;
          }
        }
        __syncthreads();
      }
      if (mm==0 && t>0 && w<NCc && wid<2) {
        const int b2 = wid*64+lane;
        float y=0.f;
        #pragma unroll
        for (int q=0; q<8; ++q) y += lds_dec[q*128 + b2];
        out[(b2*NCc + w)*Tc + (t-1)] = y + dbv;
      }

      // ---------- LSTM cell (i,f,g,o) ----------
      float hn=0.f, cn=0.f;
      if (cellw) {
        float ig = sigm(xg[0]+hacc[0]);
        float fg = sigm(xg[1]+hacc[1]);
        float gg = tanhf(xg[2]+hacc[2]);
        float og = sigm(xg[3]+hacc[3]);
        cn = fg*c + ig*gg;
        hn = og*tanhf(cn);
        gstore(hbuf + (gt&1)*HSZ + jmine*Bc + b, hn);
        gstore(stc  + (gt&1)*HSZ + jmine*Bc + b, st_run + (1.f - prev_pm)*hn);
        lds_hp[jpair*128 + b] = hn*hwj;
      }
      __syncthreads();
      if (wid < 2) {
        const int b2 = wid*64+lane;
        float h4 = (lds_hp[b2]+lds_hp[128+b2])+(lds_hp[256+b2]+lds_hp[384+b2]);
        gstore(hpp + (gt&1)*PSZ + w*Bc + b2, h4);
      }

      gsync(w);

      // ---------- phase B: replicated halting decision ----------
      {
        const int q = wid >> 1, bh2 = wid & 1;
        const int b2 = bh2*64 + lane;
        const float* hp = hpp + (gt&1)*PSZ + q*16*Bc + b2;
        float s0=0.f, s1=0.f, s2=0.f, s3=0.f;
        #pragma unroll
        for (int i4=0; i4<16; i4+=4) {
          s0 += gload(hp + (i4+0)*Bc);
          s1 += gload(hp + (i4+1)*Bc);
          s2 += gload(hp + (i4+2)*Bc);
          s3 += gload(hp + (i4+3)*Bc);
        }
        lds_hq[q*128 + b2] = (s0+s1)+(s2+s3);
      }
      __syncthreads();
      if (wid < 2) {
        const int b2 = wid*64+lane;
        float hpv=0.f;
        #pragma unroll
        for (int q=0; q<8; ++q) hpv += lds_hq[q*128 + b2];
        float pn = sigm(hpv + hb0);
        cumw += pn;
        int ok = __all(cumw >= 0.99f) ? 1 : 0;
        if (lane == 0) lds_u[wid] = (unsigned)ok;
        lds_pmh[b2] = fminf(1.f, cumw);
      }
      __syncthreads();
      int finv = (((lds_u[0] & lds_u[1]) != 0u) || (mm == Mc-1)) ? 1 : 0;

      if (wid < 2) {
        float pmf = finv ? 1.f : fminf(1.f, cumw);
        if (!ntsetw && pmf >= 1.f) {
          ntfw = (float)mm;
          rtvw = (mm == 0) ? 0.f : (1.f - prevw);
          ntsetw = true;
        }
        prevw = pmf;
      }
      if (cellw) {
        float pm = finv ? 1.f : lds_pmh[b];
        float ph = pm - prev_pm;
        st_run += ph*hn;
        ct_run += ph*cn;
        prev_pm = pm;
        c = finv ? ct_run : cn;
      }
      if (finv) {
        if (wid < 2) {
          psumw += ntfw + rtvw;
          if (w == 0) out[N_OFF + (wid*64+lane)*Tc + t] = ntfw;
          ntsetw=false; prevw=0.f; cumw=0.f; ntfw=0.f; rtvw=0.f;
        }
        if (cellw) { st_run=0.f; ct_run=0.f; prev_pm=0.f; }
        lastpar = gt & 1;
        ++gt;
        break;
      }
      ++gt;
    }
  }

  // -------- epilogue: Y for t=23, P --------
  if (w < NCc) {
    float da = 0.f;
    const float* hs = stc + lastpar*HSZ + kq*Bc + b;
    #pragma unroll 1
    for (int kk=0; kk<64; ++kk) da = fmaf(gload(hs + kk*Bc), dwq[kk], da);
    __syncthreads();
    lds_dec[k8*128 + b] = da;
    __syncthreads();
    if (wid < 2) {
      const int b2 = wid*64+lane;
      float y=0.f;
      #pragma unroll
      for (int q=0; q<8; ++q) y += lds_dec[q*128 + b2];
      out[(b2*NCc + w)*Tc + (Tc-1)] = y + dbv;
    }
  }
  if (w == 20 && wid < 2) out[P_OFF + wid*64 + lane] = psumw;
}

extern "C" void kernel_launch(void* const* d_in, const int* in_sizes, int n_in,
                              void* d_out, int out_size, void* d_ws, size_t ws_size,
                              hipStream_t stream) {
  const float* x   = (const float*)d_in[0];
  const float* Wih = (const float*)d_in[1];
  const float* Whh = (const float*)d_in[2];
  const float* bih = (const float*)d_in[3];
  const float* bhh = (const float*)d_in[4];
  const float* hw  = (const float*)d_in[5];
  const float* hb  = (const float*)d_in[6];
  const float* dwp = (const float*)d_in[7];
  const float* dbp = (const float*)d_in[8];
  float* out = (float*)d_out;
  float* ws  = (float*)d_ws;

  void* kargs[] = {(void*)&x, (void*)&Wih, (void*)&Whh, (void*)&bih, (void*)&bhh,
                   (void*)&hw, (void*)&hb, (void*)&dwp, (void*)&dbp, (void*)&out, (void*)&ws};
  hipLaunchCooperativeKernel((void*)act_lstm_kernel, dim3(NWG), dim3(TPB),
                             kargs, 0, stream);
}

// Round 11
// 2177.575 us; speedup vs baseline: 2.6313x; 2.6313x over previous
//
#include <hip/hip_runtime.h>
#include <math.h>

#define NWG 256
#define TPB 1024

static constexpr int Bc=128, Ic=256, Hc=512, NCc=16, Tc=24, Mc=14;
static constexpr int Y_SZ  = Bc*NCc*Tc;     // 49152
static constexpr int P_OFF = Y_SZ;          // 49152
static constexpr int N_OFF = Y_SZ + Bc;     // 49280

// ws layout (floats) -- total 331776 floats = 1.27 MiB (< 1.375 proven)
static constexpr int HSZ    = Hc*Bc;                  // 65536
static constexpr int HB_OFF = 0;                      // hbuf[2][512][128]
static constexpr int SC_OFF = 2*HSZ;                  // stc[2][512][128]
static constexpr int HP_OFF = 4*HSZ;                  // hpp[2][16][128]
static constexpr int DP_OFF = HP_OFF + 2*2048;        // decp[2][16][16][128]

typedef float f4v __attribute__((ext_vector_type(4)));

// Hierarchical barrier: 16 groups x 16 blocks; monotonic watermarks, 64B lines.
__device__ __align__(64) unsigned g_bcnt[16][16];
__device__ __align__(64) unsigned g_bgen[16][16];
__device__ __align__(64) unsigned g_brc[16];
__device__ __align__(64) unsigned g_brg[16];

__device__ __forceinline__ float sigm(float v){ return 1.0f/(1.0f+expf(-v)); }

// PRODUCER: system-scope write-through stores (sc0 sc1) -> coherent at IF. [r4-proven]
__device__ __forceinline__ void gstore(float* p, float v){
  __hip_atomic_store(p, v, __ATOMIC_RELAXED, __HIP_MEMORY_SCOPE_SYSTEM);
}
// CONSUMER: volatile loads -> sc0 sc1, bypass L1/XCD-L2, read at coherent IF,
// still pipeline (r9-proven correct). NO fence anywhere: plain-cached data
// (weights, x, biases) is immutable, so caches stay hot for the whole kernel.
__device__ __forceinline__ float gload(const float* p){
  return *(const volatile float*)p;
}

__device__ __forceinline__ void gsync(int w){
  __syncthreads();
  if (threadIdx.x == 0) {
    asm volatile("" ::: "memory");
    const int g = w >> 4;                    // 16 groups of 16
    unsigned prev = __hip_atomic_fetch_add(&g_bcnt[g][0], 1u, __ATOMIC_RELAXED, __HIP_MEMORY_SCOPE_SYSTEM);
    unsigned ep   = prev >> 4;
    if ((prev & 15u) == 15u) {
      unsigned rprev = __hip_atomic_fetch_add(&g_brc[0], 1u, __ATOMIC_RELAXED, __HIP_MEMORY_SCOPE_SYSTEM);
      if ((rprev & 15u) == 15u) {
        __hip_atomic_store(&g_brg[0], (rprev >> 4) + 1u, __ATOMIC_RELEASE, __HIP_MEMORY_SCOPE_SYSTEM);
      } else {
        while ((int)(__hip_atomic_load(&g_brg[0], __ATOMIC_RELAXED, __HIP_MEMORY_SCOPE_SYSTEM) - (ep + 1u)) < 0)
          __builtin_amdgcn_s_sleep(1);
      }
      __hip_atomic_store(&g_bgen[g][0], ep + 1u, __ATOMIC_RELEASE, __HIP_MEMORY_SCOPE_SYSTEM);
    } else {
      while ((int)(__hip_atomic_load(&g_bgen[g][0], __ATOMIC_RELAXED, __HIP_MEMORY_SCOPE_SYSTEM) - (ep + 1u)) < 0)
        __builtin_amdgcn_s_sleep(1);
    }
    asm volatile("" ::: "memory");
  }
  __syncthreads();
}

__global__ __launch_bounds__(TPB, 1) void act_lstm_kernel(
    const float* __restrict__ x,   const float* __restrict__ Wih,
    const float* __restrict__ Whh, const float* __restrict__ bih,
    const float* __restrict__ bhh, const float* __restrict__ hw,
    const float* __restrict__ hbp, const float* __restrict__ dw,
    const float* __restrict__ db,  float* __restrict__ out,
    float* __restrict__ ws)
{
  const int w    = blockIdx.x;
  const int tid  = threadIdx.x;
  const int lane = tid & 63;
  const int wid  = __builtin_amdgcn_readfirstlane(tid >> 6); // 0..15 = k/i-chunk
  const int bg   = w >> 4;           // batch group: b in [bg*8, bg*8+8)
  const int js   = w & 15;           // j-slice: j in [js*32, js*32+32)
  const int kg   = wid;              // wave's k-chunk (h: 32 k, x: 16 i)
  // lanes own global rows {lane, lane+64} of this block's 128 gate rows
  const int rl0  = lane, rl1 = lane + 64;
  const int grow0 = ((rl0>>5)<<9) + js*32 + (rl0&31);
  const int grow1 = ((rl1>>5)<<9) + js*32 + (rl1&31);
  // cell ownership (threads 0..255): (jloc, bl)
  const bool iscell = (tid < 256);
  const int jloc = tid >> 3, bl = tid & 7;          // valid when iscell
  const int jglob = js*32 + jloc;
  const int bglob = bg*8 + bl;

  float* hbuf = ws + HB_OFF;
  float* stc  = ws + SC_OFF;
  float* hpp  = ws + HP_OFF;
  float* decp = ws + DP_OFF;

  __shared__ float h_lds[4096];       // [j 512][b 8]
  __shared__ float x_lds[2048];       // [i 256][b 8]
  __shared__ float part[128*129];     // [row][kg*8+b], stride 129 (bank-clean)
  __shared__ float sums[1024];        // [row*8+b]
  __shared__ float dp[4096];          // [nc 16][jloc 32][b 8]
  __shared__ float hp[256];
  __shared__ float pmh[128];
  __shared__ unsigned ldsu[2];

  const f4v* Wh0 = (const f4v*)(Whh + grow0*Hc) + kg*8;  // 8 f4 (32 k)
  const f4v* Wh1 = (const f4v*)(Whh + grow1*Hc) + kg*8;
  const f4v* Wx0 = (const f4v*)(Wih + grow0*Ic) + kg*4;  // 4 f4 (16 i)
  const f4v* Wx1 = (const f4v*)(Wih + grow1*Ic) + kg*4;

  float bsum[4] = {0,0,0,0};
  float hwj = 0.f;
  if (iscell) {
    #pragma unroll
    for (int g=0; g<4; ++g) bsum[g] = bih[g*512 + jglob] + bhh[g*512 + jglob];
    hwj = hw[jglob];
  }
  const float hb0 = hbp[0];

  // persistent state
  float c = 0.f, st_run = 0.f, ct_run = 0.f, prev_pm = 0.f;          // cell
  float cumw=0.f, prevw=0.f, ntfw=0.f, rtvw=0.f, psumw=0.f;          // tracker (wid<2)
  bool  ntsetw = false;
  int   gt = 0, lastpar = 0, pend_t = -1, pend_par = 0;
  float xg[4] = {0,0,0,0};

  for (int t = 0; t < Tc; ++t) {
    for (int mm = 0;; ++mm) {
      const bool do_h = !(mm == 0 && t == 0);
      float xv0 = 0.f, xv1 = 0.f;
      if (mm == 0) {
        const int i0 = tid >> 3, b0 = tid & 7;
        const int xb = (bg*8 + b0) * (Ic*Tc);
        xv0 = x[xb + i0*Tc + t];
        xv1 = x[xb + (i0+128)*Tc + t];
      }
      // ---- load h slice (one volatile float4 per thread) ----
      if (do_h) {
        const float* src = (mm == 0) ? (stc + lastpar*HSZ) : (hbuf + ((gt-1)&1)*HSZ);
        const int j = tid >> 1, q = tid & 1;
        f4v hv = *(const volatile f4v*)(src + j*128 + bg*8 + q*4);
        *(f4v*)&h_lds[tid*4] = hv;
      }
      __syncthreads();

      if (mm == 0) {
        x_lds[tid]        = xv0;       // layout [i*8+b] == tid
        x_lds[tid + 1024] = xv1;
        __syncthreads();
        // ---- x-GEMV: rows {rl0,rl1} x i-chunk 16 x 8 b ----
        float a0[8] = {0,0,0,0,0,0,0,0}, a1[8] = {0,0,0,0,0,0,0,0};
        #pragma unroll
        for (int c4 = 0; c4 < 4; ++c4) {
          f4v w0 = Wx0[c4], w1 = Wx1[c4];
          #pragma unroll
          for (int d = 0; d < 4; ++d) {
            const float wa = w0[d], wb = w1[d];
            const float* hbp_ = &x_lds[(kg*16 + c4*4 + d)*8];
            f4v hA = *(const f4v*)hbp_, hB = *(const f4v*)(hbp_+4);
            a0[0]=fmaf(wa,hA.x,a0[0]); a0[1]=fmaf(wa,hA.y,a0[1]);
            a0[2]=fmaf(wa,hA.z,a0[2]); a0[3]=fmaf(wa,hA.w,a0[3]);
            a0[4]=fmaf(wa,hB.x,a0[4]); a0[5]=fmaf(wa,hB.y,a0[5]);
            a0[6]=fmaf(wa,hB.z,a0[6]); a0[7]=fmaf(wa,hB.w,a0[7]);
            a1[0]=fmaf(wb,hA.x,a1[0]); a1[1]=fmaf(wb,hA.y,a1[1]);
            a1[2]=fmaf(wb,hA.z,a1[2]); a1[3]=fmaf(wb,hA.w,a1[3]);
            a1[4]=fmaf(wb,hB.x,a1[4]); a1[5]=fmaf(wb,hB.y,a1[5]);
            a1[6]=fmaf(wb,hB.z,a1[6]); a1[7]=fmaf(wb,hB.w,a1[7]);
          }
        }
        #pragma unroll
        for (int b = 0; b < 8; ++b) {
          part[rl0*129 + kg*8 + b] = a0[b];
          part[rl1*129 + kg*8 + b] = a1[b];
        }
        __syncthreads();
        { // stage1 reduce over kg
          const int row = tid >> 3, b = tid & 7;
          float s = 0.f;
          #pragma unroll
          for (int q2 = 0; q2 < 16; ++q2) s += part[row*129 + q2*8 + b];
          sums[tid] = s;
        }
        __syncthreads();
        if (iscell) {
          #pragma unroll
          for (int g = 0; g < 4; ++g) xg[g] = bsum[g] + sums[(g*32 + jloc)*8 + bl];
        }
        __syncthreads();   // part/sums free for h round
      }

      // ---- h-GEMV: rows {rl0,rl1} x k-chunk 32 x 8 b ----
      {
        float a0[8] = {0,0,0,0,0,0,0,0}, a1[8] = {0,0,0,0,0,0,0,0};
        if (do_h) {
          #pragma unroll
          for (int c4 = 0; c4 < 8; ++c4) {
            f4v w0 = Wh0[c4], w1 = Wh1[c4];
            #pragma unroll
            for (int d = 0; d < 4; ++d) {
              const float wa = w0[d], wb = w1[d];
              const float* hbp_ = &h_lds[(kg*32 + c4*4 + d)*8];
              f4v hA = *(const f4v*)hbp_, hB = *(const f4v*)(hbp_+4);
              a0[0]=fmaf(wa,hA.x,a0[0]); a0[1]=fmaf(wa,hA.y,a0[1]);
              a0[2]=fmaf(wa,hA.z,a0[2]); a0[3]=fmaf(wa,hA.w,a0[3]);
              a0[4]=fmaf(wa,hB.x,a0[4]); a0[5]=fmaf(wa,hB.y,a0[5]);
              a0[6]=fmaf(wa,hB.z,a0[6]); a0[7]=fmaf(wa,hB.w,a0[7]);
              a1[0]=fmaf(wb,hA.x,a1[0]); a1[1]=fmaf(wb,hA.y,a1[1]);
              a1[2]=fmaf(wb,hA.z,a1[2]); a1[3]=fmaf(wb,hA.w,a1[3]);
              a1[4]=fmaf(wb,hB.x,a1[4]); a1[5]=fmaf(wb,hB.y,a1[5]);
              a1[6]=fmaf(wb,hB.z,a1[6]); a1[7]=fmaf(wb,hB.w,a1[7]);
            }
          }
        }
        #pragma unroll
        for (int b = 0; b < 8; ++b) {
          part[rl0*129 + kg*8 + b] = a0[b];
          part[rl1*129 + kg*8 + b] = a1[b];
        }
      }
      __syncthreads();
      {
        const int row = tid >> 3, b = tid & 7;
        float s = 0.f;
        #pragma unroll
        for (int q2 = 0; q2 < 16; ++q2) s += part[row*129 + q2*8 + b];
        sums[tid] = s;
      }
      __syncthreads();

      // ---- LSTM cell (i,f,g,o) ----
      float hn = 0.f, cn = 0.f;
      if (iscell) {
        float g0 = xg[0] + sums[(0*32 + jloc)*8 + bl];
        float g1 = xg[1] + sums[(1*32 + jloc)*8 + bl];
        float g2 = xg[2] + sums[(2*32 + jloc)*8 + bl];
        float g3 = xg[3] + sums[(3*32 + jloc)*8 + bl];
        float ig = sigm(g0), fg = sigm(g1), gg = tanhf(g2), og = sigm(g3);
        cn = fg*c + ig*gg;
        hn = og*tanhf(cn);
        const int par = gt & 1;
        gstore(hbuf + par*HSZ + jglob*128 + bglob, hn);
        gstore(stc  + par*HSZ + jglob*128 + bglob, st_run + (1.f - prev_pm)*hn);
        hp[tid] = hn * hwj;
      }
      __syncthreads();
      if (tid < 8) {
        float s = 0.f;
        #pragma unroll
        for (int jl = 0; jl < 32; ++jl) s += hp[jl*8 + tid];
        gstore(hpp + (gt&1)*2048 + js*128 + bg*8 + tid, s);
      }

      gsync(w);

      // ---- phase B ----
      if (pend_t >= 0) {            // Y for previous timestep (decp visible now)
        if (js == 0 && tid < 128) {
          const int nc = tid >> 3, b2 = tid & 7;
          float y = 0.f;
          #pragma unroll
          for (int q2 = 0; q2 < 16; ++q2)
            y += gload(decp + pend_par*32768 + q2*2048 + nc*128 + bg*8 + b2);
          out[((bg*8 + b2)*NCc + nc)*Tc + pend_t] = y + db[nc];
        }
        pend_t = -1;
      }
      const int par = gt & 1;
      if (wid < 2) {
        const int b2 = wid*64 + lane;
        float hsum = 0.f;
        #pragma unroll
        for (int q2 = 0; q2 < 16; ++q2) hsum += gload(hpp + par*2048 + q2*128 + b2);
        float pn = sigm(hsum + hb0);
        cumw += pn;
        int ok = __all(cumw >= 0.99f) ? 1 : 0;
        if (lane == 0) ldsu[wid] = (unsigned)ok;
        pmh[b2] = fminf(1.f, cumw);
      }
      __syncthreads();
      const int finv = (((ldsu[0] & ldsu[1]) != 0u) || (mm == Mc-1)) ? 1 : 0;

      if (wid < 2) {
        float pmf = finv ? 1.f : fminf(1.f, cumw);
        if (!ntsetw && pmf >= 1.f) {
          ntfw = (float)mm;
          rtvw = (mm == 0) ? 0.f : (1.f - prevw);
          ntsetw = true;
        }
        prevw = pmf;
      }
      if (iscell) {
        float pm = finv ? 1.f : pmh[bglob];
        float ph = pm - prev_pm;
        st_run += ph*hn;
        ct_run += ph*cn;
        prev_pm = pm;
        c = finv ? ct_run : cn;
      }
      if (finv) {
        if (iscell) {
          #pragma unroll
          for (int nc = 0; nc < 16; ++nc)
            dp[nc*256 + tid] = dw[nc*512 + jglob] * st_run;
        }
        __syncthreads();
        if (tid < 128) {
          const int nc = tid >> 3, b2 = tid & 7;
          float s = 0.f;
          #pragma unroll
          for (int jl = 0; jl < 32; ++jl) s += dp[nc*256 + jl*8 + b2];
          gstore(decp + par*32768 + js*2048 + nc*128 + bg*8 + b2, s);
        }
        if (w == 0 && wid < 2)
          out[N_OFF + (wid*64 + lane)*Tc + t] = ntfw;
        if (wid < 2) {
          psumw += ntfw + rtvw;
          ntsetw = false; prevw = 0.f; cumw = 0.f; ntfw = 0.f; rtvw = 0.f;
        }
        if (iscell) { st_run = 0.f; ct_run = 0.f; prev_pm = 0.f; }
        pend_t = t; pend_par = par; lastpar = par;
      }
      ++gt;
      if (finv) break;
    }
  }

  // ---- epilogue: Y for t=23, P ----
  gsync(w);
  if (pend_t >= 0 && js == 0 && tid < 128) {
    const int nc = tid >> 3, b2 = tid & 7;
    float y = 0.f;
    #pragma unroll
    for (int q2 = 0; q2 < 16; ++q2)
      y += gload(decp + pend_par*32768 + q2*2048 + nc*128 + bg*8 + b2);
    out[((bg*8 + b2)*NCc + nc)*Tc + pend_t] = y + db[nc];
  }
  if (w == 1 && wid < 2) out[P_OFF + wid*64 + lane] = psumw;
}

extern "C" void kernel_launch(void* const* d_in, const int* in_sizes, int n_in,
                              void* d_out, int out_size, void* d_ws, size_t ws_size,
                              hipStream_t stream) {
  const float* x   = (const float*)d_in[0];
  const float* Wih = (const float*)d_in[1];
  const float* Whh = (const float*)d_in[2];
  const float* bih = (const float*)d_in[3];
  const float* bhh = (const float*)d_in[4];
  const float* hw  = (const float*)d_in[5];
  const float* hb  = (const float*)d_in[6];
  const float* dwp = (const float*)d_in[7];
  const float* dbp = (const float*)d_in[8];
  float* out = (float*)d_out;
  float* ws  = (float*)d_ws;

  void* kargs[] = {(void*)&x, (void*)&Wih, (void*)&Whh, (void*)&bih, (void*)&bhh,
                   (void*)&hw, (void*)&hb, (void*)&dwp, (void*)&dbp, (void*)&out, (void*)&ws};
  hipLaunchCooperativeKernel((void*)act_lstm_kernel, dim3(NWG), dim3(TPB),
                             kargs, 0, stream);
}